// Round 2
// baseline (948.554 us; speedup 1.0000x reference)
//
#include <hip/hip_runtime.h>

// Fused 5-iteration Jacobi, cross-stencil, B=16, H=W=1024 fp32.
// R6: LDS-pipe diet on top of R5's in-place 32KiB/4-blocks-per-CU structure.
//  - Register-resident center rows: each thread keeps its 4 rows (f2..f5) in
//    VGPRs across sweeps (they equal its previous outputs). Per-sweep LDS
//    reads drop 8 b128 -> 4 b128 (y-halo rows from neighboring quads only).
//  - x-halos via __shfl (ds_bpermute crossbar, conflict-free): neighbor LANES
//    hold cols c-2,c-1 / c+4,c+5 in their center registers. Removes all 8
//    conflicted float2 LDS reads per sweep (was 1.31e7 conflict cycles).
//    Lane-boundary garbage stays outside the 5-sweep dependency cone of the
//    stored 104x40 center (same cone argument as the old wrap-around reads).
//  - Final sweep stores straight from registers: no sweep-5 LDS write/barriers
//    and no separate store phase (9 barriers/block instead of 11).
//  - XCD-chunked block swizzle (bijective, 4160 = 8*520): x/y-adjacent tiles
//    share an XCD's L2 so partial 64B store lines at tile boundaries merge
//    (R5 write amplification: WRITE_SIZE 65.5 -> 110 MB) and halo re-fetches
//    hit L2.
// Geometry unchanged: row = 128 floats, stride % 32 banks == 0, b128 phases
// conflict-free. Tile 128x64, output 104x40/block, grid 10x26x16, 5 in-place
// sweeps (read-to-regs -> barrier -> write -> barrier), EDGE mask on ring.

#define HH 1024
#define WW 1024
#define NB 16
#define GX 10              // ceil(1024/TX)
#define GY 26              // ceil(1024/TY)
#define TX 104
#define TY 40
#define HALO 12
#define TWX 128            // LDS row width == stride (floats)
#define TWY 64             // TY + 2*HALO
#define NGX 32             // float4 groups per row
#define NITER 5
#define NTHREADS 512
#define NQ 15              // row quads covering rows [2,62)
#define NITEMS (NQ * NGX)  // 480
#define NBLK (GX * GY * NB)   // 4160
#define NXCD 8
#define CHUNK (NBLK / NXCD)   // 520 (exact: 4160 % 8 == 0 -> bijective)

struct Coef { float sH1, sH2, sW1, sW2; };

__device__ __forceinline__ float4 ld4(const float* p) { return *(const float4*)p; }

template <bool EDGE>
__device__ __forceinline__ float4 upd_row(
    const float4 a2, const float4 a1, const float4 ct, const float4 b1, const float4 b2,
    const float2 hm, const float2 hp, const float4 rv, const Coef cf,
    const int gy, const int gx0)
{
    const float A2[4] = {a2.x, a2.y, a2.z, a2.w};
    const float A1[4] = {a1.x, a1.y, a1.z, a1.w};
    const float CT[4] = {ct.x, ct.y, ct.z, ct.w};
    const float B1[4] = {b1.x, b1.y, b1.z, b1.w};
    const float B2[4] = {b2.x, b2.y, b2.z, b2.w};
    const float RV[4] = {rv.x, rv.y, rv.z, rv.w};
    const float cc[8] = {hm.x, hm.y, ct.x, ct.y, ct.z, ct.w, hp.x, hp.y};
    const bool rowok = (gy >= 2) && (gy < HH - 2);
    float o[4];
#pragma unroll
    for (int k = 0; k < 4; ++k) {
        float v = RV[k];
        v = fmaf(cf.sH2, A2[k] + B2[k], v);
        v = fmaf(cf.sH1, A1[k] + B1[k], v);
        v = fmaf(cf.sW2, cc[k] + cc[k + 4], v);
        v = fmaf(cf.sW1, cc[k + 1] + cc[k + 3], v);
        if (EDGE) {
            const int gx = gx0 + k;
            const bool ok = rowok && (gx >= 2) && (gx < WW - 2);
            v = ok ? v : CT[k];
        }
        o[k] = v;
    }
    return make_float4(o[0], o[1], o[2], o[3]);
}

template <bool EDGE>
__device__ __forceinline__ void sweeps_store(
    float* buf, const bool active, const int r, const int c,
    const int gx0, const int gy0, const float4* rv, const Coef cf,
    float* ob, const int x0, const int y0)
{
    float* s = buf + r * TWX + c;
    const int lane = (int)(threadIdx.x & 63);
    const int lm = (lane + 63) & 63;   // left neighbor lane (wrap = cone-safe garbage)
    const int lp = (lane + 1) & 63;    // right neighbor lane

    // center rows live in registers across sweeps (init to finite values so
    // inactive lanes feed finite garbage into boundary shuffles)
    float4 f2 = {0,0,0,0}, f3 = {0,0,0,0}, f4 = {0,0,0,0}, f5 = {0,0,0,0};
    if (active) {
        f2 = ld4(s);
        f3 = ld4(s + 1 * TWX);
        f4 = ld4(s + 2 * TWX);
        f5 = ld4(s + 3 * TWX);
    }

#pragma unroll
    for (int it = 0; it < NITER; ++it) {
        // x-halos from neighbor lanes' registers — ALL lanes execute (shuffle
        // sources include ring lanes), ds_bpermute = no bank conflicts
        const float2 h0m = make_float2(__shfl(f2.z, lm, 64), __shfl(f2.w, lm, 64));
        const float2 h0p = make_float2(__shfl(f2.x, lp, 64), __shfl(f2.y, lp, 64));
        const float2 h1m = make_float2(__shfl(f3.z, lm, 64), __shfl(f3.w, lm, 64));
        const float2 h1p = make_float2(__shfl(f3.x, lp, 64), __shfl(f3.y, lp, 64));
        const float2 h2m = make_float2(__shfl(f4.z, lm, 64), __shfl(f4.w, lm, 64));
        const float2 h2p = make_float2(__shfl(f4.x, lp, 64), __shfl(f4.y, lp, 64));
        const float2 h3m = make_float2(__shfl(f5.z, lm, 64), __shfl(f5.w, lm, 64));
        const float2 h3p = make_float2(__shfl(f5.x, lp, 64), __shfl(f5.y, lp, 64));

        float4 o0, o1, o2, o3;
        if (active) {
            const float4 f0 = ld4(s - 2 * TWX);   // y-halo rows from neighbor quads
            const float4 f1 = ld4(s - 1 * TWX);
            const float4 f6 = ld4(s + 4 * TWX);
            const float4 f7 = ld4(s + 5 * TWX);
            o0 = upd_row<EDGE>(f0, f1, f2, f3, f4, h0m, h0p, rv[0], cf, gy0 + 0, gx0);
            o1 = upd_row<EDGE>(f1, f2, f3, f4, f5, h1m, h1p, rv[1], cf, gy0 + 1, gx0);
            o2 = upd_row<EDGE>(f2, f3, f4, f5, f6, h2m, h2p, rv[2], cf, gy0 + 2, gx0);
            o3 = upd_row<EDGE>(f3, f4, f5, f6, f7, h3m, h3p, rv[3], cf, gy0 + 3, gx0);
        }
        if (it < NITER - 1) {
            __syncthreads();   // all reads of iteration `it` retired
            if (active) {
                *(float4*)(s)           = o0;
                *(float4*)(s + 1 * TWX) = o1;
                *(float4*)(s + 2 * TWX) = o2;
                *(float4*)(s + 3 * TWX) = o3;
                f2 = o0; f3 = o1; f4 = o2; f5 = o3;
            }
            __syncthreads();   // writes visible before next read phase
        } else if (active) {
            // final sweep: store straight from registers (center ∩ bounds)
            const float4 oo[4] = {o0, o1, o2, o3};
            const int gxl = x0 + (c - HALO);
            const bool colok = (c >= HALO) && (c < HALO + TX) && (gxl <= WW - 4);
#pragma unroll
            for (int j = 0; j < 4; ++j) {
                const int ly = r + j;
                const int gy = y0 + (ly - HALO);
                if (colok && ly >= HALO && ly < HALO + TY && gy < HH)
                    *(float4*)(ob + (size_t)gy * WW + gxl) = oo[j];
            }
        }
    }
}

__global__ __launch_bounds__(NTHREADS, 8) void jacobi_fused(
    const float* __restrict__ g0, const float* __restrict__ rhs,
    const float* __restrict__ dx, float* __restrict__ out)
{
    __shared__ __align__(16) float buf[TWY * TWX];   // 32 KiB -> 4 blocks/CU

    const int tid = (int)threadIdx.x;

    // ---- XCD-chunked block swizzle: consecutive logical tiles land on the
    //      same XCD's L2 (hardware round-robins wg -> XCD by dispatch index)
    const int h = (int)blockIdx.x + GX * ((int)blockIdx.y + GY * (int)blockIdx.z);
    const int l = (h & (NXCD - 1)) * CHUNK + (h >> 3);
    const int tx = l % GX;
    const int t2 = l / GX;
    const int ty = t2 % GY;
    const int b  = t2 / GY;

    const int x0 = tx * TX, y0 = ty * TY;

    const float* gb = g0 + (size_t)b * HH * WW;
    const float* rb = rhs + (size_t)b * HH * WW;
    float* ob = out + (size_t)b * HH * WW;

    // per-batch coefficients (d_inv and the -cr sign folded in)
    const float t0 = 1.0f / dx[2 * b + 0], t1 = 1.0f / dx[2 * b + 1];
    const float p0 = t0 * t0, p1 = t1 * t1;
    const float d_inv = 1.0f / (-2.5f * (p0 + p1));
    Coef cf;
    cf.sH1 = -d_inv * (4.0f / 3.0f) * p0;
    cf.sH2 = -d_inv * (-1.0f / 12.0f) * p0;
    cf.sW1 = -d_inv * (4.0f / 3.0f) * p1;
    cf.sW2 = -d_inv * (-1.0f / 12.0f) * p1;

    // ---- fixed work item: 4 rows x 4 cols; lane%32 == col group -> b128 phases
    //      are 32-bank aligned ----
    const bool active = tid < NITEMS;
    const int q = tid >> 5;            // row quad 0..14
    const int cg = tid & 31;           // col group 0..31
    const int r = 2 + 4 * q;           // rows r..r+3 in [2,62)
    const int c = 4 * cg;              // cols c..c+3 in [0,128)
    const int gx0 = x0 - HALO + c;
    const int gy0 = y0 - HALO + r;

    // rhs * d_inv preload (clamped; clamped lanes only feed masked/garbage points)
    float4 rv[4] = {};
    if (active) {
        int gxc = gx0 < 0 ? 0 : (gx0 > WW - 4 ? WW - 4 : gx0);
#pragma unroll
        for (int j = 0; j < 4; ++j) {
            int gy = gy0 + j;
            gy = gy < 0 ? 0 : (gy > HH - 1 ? HH - 1 : gy);
            float4 v = *(const float4*)(rb + (size_t)gy * WW + gxc);
            rv[j] = make_float4(d_inv * v.x, d_inv * v.y, d_inv * v.z, d_inv * v.w);
        }
    }

    // ---- load 128x64 input tile into buf (clamp-replicate at domain edges) ----
#pragma unroll
    for (int tt = 0; tt < (TWY * NGX) / NTHREADS; ++tt) {
        const int t = tid + tt * NTHREADS;
        const int ly = t >> 5;
        const int c4 = (t & 31) * 4;
        int gy = y0 - HALO + ly;
        gy = gy < 0 ? 0 : (gy > HH - 1 ? HH - 1 : gy);
        const int gxl = x0 - HALO + c4;
        const float* row = gb + (size_t)gy * WW;
        float4 v;
        if (gxl >= 0 && gxl <= WW - 4) {
            v = *(const float4*)(row + gxl);
        } else {
            int xa = gxl + 0; xa = xa < 0 ? 0 : (xa > WW - 1 ? WW - 1 : xa);
            int xb = gxl + 1; xb = xb < 0 ? 0 : (xb > WW - 1 ? WW - 1 : xb);
            int xc = gxl + 2; xc = xc < 0 ? 0 : (xc > WW - 1 ? WW - 1 : xc);
            int xd = gxl + 3; xd = xd < 0 ? 0 : (xd > WW - 1 ? WW - 1 : xd);
            v = make_float4(row[xa], row[xb], row[xc], row[xd]);
        }
        *(float4*)(&buf[ly * TWX + c4]) = v;
    }
    __syncthreads();

    // interior fast path (conservative: dependency cone of the stored center
    // strictly inside the frozen ring)
    const bool interior = (x0 - HALO >= 2) && (x0 + TX + HALO <= WW - 2) &&
                          (y0 - HALO >= 2) && (y0 + TY + HALO <= HH - 2);
    if (interior) sweeps_store<false>(buf, active, r, c, gx0, gy0, rv, cf, ob, x0, y0);
    else          sweeps_store<true >(buf, active, r, c, gx0, gy0, rv, cf, ob, x0, y0);
}

extern "C" void kernel_launch(void* const* d_in, const int* in_sizes, int n_in,
                              void* d_out, int out_size, void* d_ws, size_t ws_size,
                              hipStream_t stream) {
    const float* g0  = (const float*)d_in[0];
    const float* rhs = (const float*)d_in[1];
    const float* dx  = (const float*)d_in[2];
    float* out = (float*)d_out;

    dim3 grid(GX, GY, NB), block(NTHREADS);
    jacobi_fused<<<grid, block, 0, stream>>>(g0, rhs, dx, out);
}

// Round 3
// 220.542 us; speedup vs baseline: 4.3010x; 4.3010x over previous
//
#include <hip/hip_runtime.h>

// Fused 5-iteration Jacobi, cross-stencil, B=16, H=W=1024 fp32.
// R7 = R6's LDS-diet ideas with the spill fixed and R4's barrier economy:
//  - PING-PONG buffers (1 barrier/sweep, 5 barriers total) -- R5/R6's in-place
//    2-barriers/sweep + write-amp regime regressed (114.5 -> 127 us).
//  - Center rows f2..f5 live in VGPRs across sweeps (they equal this thread's
//    previous outputs). Per-sweep LDS: 4 y-halo b128 reads + 4 b128 writes
//    + 16 ds_bpermute (x-halos from neighbor lanes) ~= 170 cyc/wave vs R4's
//    271 (which included 1.32e7 bank-conflict cycles from float2 halo reads).
//  - __launch_bounds__(512, 4): 128-VGPR cap. R6's cap of 64 spilled the
//    persistent state to scratch (FETCH 169MB -> 1.36GB, WRITE 110MB -> 1.87GB,
//    VALUBusy 0.7%). Live set here ~95 regs; occupancy is LDS-bound at
//    2 blocks/CU regardless (64 KiB), and R4/R5 showed occupancy isn't the
//    binding constraint.
//  - Final sweep stores straight from registers (no LDS store phase).
//  - XCD-chunked block swizzle (bijective, 4160 = 8*520) for L2 locality of
//    halo refetches and boundary store-line merging.
// Geometry unchanged: 128x64 tile, row stride 128 floats (%32 banks == 0),
// b128 phases conflict-free; output 104x40/block, grid 10x26x16, EDGE mask
// only on ring blocks; lane-boundary shuffle garbage and frozen rows 0,1,62,63
// stay outside the 5-sweep dependency cone of the stored center (cols [12,116)
// depend on cols [2,126), rows [12,52) depend on rows [2,62)).

#define HH 1024
#define WW 1024
#define NB 16
#define GX 10              // ceil(1024/TX)
#define GY 26              // ceil(1024/TY)
#define TX 104
#define TY 40
#define HALO 12
#define TWX 128            // LDS row width == stride (floats)
#define TWY 64             // TY + 2*HALO
#define NGX 32             // float4 groups per row
#define NITER 5
#define NTHREADS 512
#define NQ 15              // row quads covering rows [2,62)
#define NITEMS (NQ * NGX)  // 480
#define NBLK (GX * GY * NB)   // 4160
#define NXCD 8
#define CHUNK (NBLK / NXCD)   // 520 (exact: 4160 % 8 == 0 -> bijective)

struct Coef { float sH1, sH2, sW1, sW2; };

__device__ __forceinline__ float4 ld4(const float* p) { return *(const float4*)p; }

template <bool EDGE>
__device__ __forceinline__ float4 upd_row(
    const float4 a2, const float4 a1, const float4 ct, const float4 b1, const float4 b2,
    const float2 hm, const float2 hp, const float4 rv, const Coef cf,
    const int gy, const int gx0)
{
    const float A2[4] = {a2.x, a2.y, a2.z, a2.w};
    const float A1[4] = {a1.x, a1.y, a1.z, a1.w};
    const float CT[4] = {ct.x, ct.y, ct.z, ct.w};
    const float B1[4] = {b1.x, b1.y, b1.z, b1.w};
    const float B2[4] = {b2.x, b2.y, b2.z, b2.w};
    const float RV[4] = {rv.x, rv.y, rv.z, rv.w};
    const float cc[8] = {hm.x, hm.y, ct.x, ct.y, ct.z, ct.w, hp.x, hp.y};
    const bool rowok = (gy >= 2) && (gy < HH - 2);
    float o[4];
#pragma unroll
    for (int k = 0; k < 4; ++k) {
        float v = RV[k];
        v = fmaf(cf.sH2, A2[k] + B2[k], v);
        v = fmaf(cf.sH1, A1[k] + B1[k], v);
        v = fmaf(cf.sW2, cc[k] + cc[k + 4], v);
        v = fmaf(cf.sW1, cc[k + 1] + cc[k + 3], v);
        if (EDGE) {
            const int gx = gx0 + k;
            const bool ok = rowok && (gx >= 2) && (gx < WW - 2);
            v = ok ? v : CT[k];
        }
        o[k] = v;
    }
    return make_float4(o[0], o[1], o[2], o[3]);
}

template <bool EDGE>
__device__ __forceinline__ void sweeps_store(
    float* bufA, float* bufB, const bool active, const int r, const int c,
    const int gx0, const int gy0, const float4* rv, const Coef cf,
    float* ob, const int x0, const int y0)
{
    float* sA = bufA + r * TWX + c;   // sweep sources alternate A,B,A,B,A
    float* sB = bufB + r * TWX + c;
    const int lane = (int)(threadIdx.x & 63);
    const int lm = (lane + 63) & 63;   // left neighbor lane (wrap = cone-safe garbage)
    const int lp = (lane + 1) & 63;    // right neighbor lane

    // center rows live in registers across sweeps (init finite so inactive
    // lanes feed finite garbage into boundary shuffles)
    float4 f2 = {0,0,0,0}, f3 = {0,0,0,0}, f4 = {0,0,0,0}, f5 = {0,0,0,0};
    if (active) {
        f2 = ld4(sA);
        f3 = ld4(sA + 1 * TWX);
        f4 = ld4(sA + 2 * TWX);
        f5 = ld4(sA + 3 * TWX);
    }

#pragma unroll
    for (int it = 0; it < NITER; ++it) {
        const float* src = (it & 1) ? sB : sA;
        float*       dst = (it & 1) ? sA : sB;

        // x-halos from neighbor lanes' registers — ALL lanes execute
        // (ds_bpermute crossbar: no bank conflicts, no LDS data hazard)
        const float2 h0m = make_float2(__shfl(f2.z, lm, 64), __shfl(f2.w, lm, 64));
        const float2 h0p = make_float2(__shfl(f2.x, lp, 64), __shfl(f2.y, lp, 64));
        const float2 h1m = make_float2(__shfl(f3.z, lm, 64), __shfl(f3.w, lm, 64));
        const float2 h1p = make_float2(__shfl(f3.x, lp, 64), __shfl(f3.y, lp, 64));
        const float2 h2m = make_float2(__shfl(f4.z, lm, 64), __shfl(f4.w, lm, 64));
        const float2 h2p = make_float2(__shfl(f4.x, lp, 64), __shfl(f4.y, lp, 64));
        const float2 h3m = make_float2(__shfl(f5.z, lm, 64), __shfl(f5.w, lm, 64));
        const float2 h3p = make_float2(__shfl(f5.x, lp, 64), __shfl(f5.y, lp, 64));

        float4 o0, o1, o2, o3;
        if (active) {
            const float4 f0 = ld4(src - 2 * TWX);   // y-halo rows from neighbor quads
            const float4 f1 = ld4(src - 1 * TWX);
            const float4 f6 = ld4(src + 4 * TWX);
            const float4 f7 = ld4(src + 5 * TWX);
            o0 = upd_row<EDGE>(f0, f1, f2, f3, f4, h0m, h0p, rv[0], cf, gy0 + 0, gx0);
            o1 = upd_row<EDGE>(f1, f2, f3, f4, f5, h1m, h1p, rv[1], cf, gy0 + 1, gx0);
            o2 = upd_row<EDGE>(f2, f3, f4, f5, f6, h2m, h2p, rv[2], cf, gy0 + 2, gx0);
            o3 = upd_row<EDGE>(f3, f4, f5, f6, f7, h3m, h3p, rv[3], cf, gy0 + 3, gx0);
        }
        if (it < NITER - 1) {
            if (active) {
                *(float4*)(dst)           = o0;   // ping-pong: no read/write overlap
                *(float4*)(dst + 1 * TWX) = o1;   // within a sweep -> single barrier
                *(float4*)(dst + 2 * TWX) = o2;
                *(float4*)(dst + 3 * TWX) = o3;
                f2 = o0; f3 = o1; f4 = o2; f5 = o3;
            }
            __syncthreads();   // writes visible before next sweep's halo reads
        } else if (active) {
            // final sweep: store straight from registers (center ∩ bounds)
            const int gxl = x0 + (c - HALO);
            const bool colok = (c >= HALO) && (c < HALO + TX) && (gxl <= WW - 4);
            if (colok) {
                const int gy_0 = y0 + (r - HALO);
                if (r + 0 >= HALO && r + 0 < HALO + TY && gy_0 + 0 < HH)
                    *(float4*)(ob + (size_t)(gy_0 + 0) * WW + gxl) = o0;
                if (r + 1 >= HALO && r + 1 < HALO + TY && gy_0 + 1 < HH)
                    *(float4*)(ob + (size_t)(gy_0 + 1) * WW + gxl) = o1;
                if (r + 2 >= HALO && r + 2 < HALO + TY && gy_0 + 2 < HH)
                    *(float4*)(ob + (size_t)(gy_0 + 2) * WW + gxl) = o2;
                if (r + 3 >= HALO && r + 3 < HALO + TY && gy_0 + 3 < HH)
                    *(float4*)(ob + (size_t)(gy_0 + 3) * WW + gxl) = o3;
            }
        }
    }
}

__global__ __launch_bounds__(NTHREADS, 4) void jacobi_fused(
    const float* __restrict__ g0, const float* __restrict__ rhs,
    const float* __restrict__ dx, float* __restrict__ out)
{
    __shared__ __align__(16) float bufA[TWY * TWX];   // ping
    __shared__ __align__(16) float bufB[TWY * TWX];   // pong (64 KiB -> 2 blocks/CU)

    const int tid = (int)threadIdx.x;

    // ---- XCD-chunked block swizzle: consecutive logical tiles land on the
    //      same XCD's L2 (hardware round-robins wg -> XCD by dispatch index)
    const int h = (int)blockIdx.x + GX * ((int)blockIdx.y + GY * (int)blockIdx.z);
    const int l = (h & (NXCD - 1)) * CHUNK + (h >> 3);
    const int tx = l % GX;
    const int t2 = l / GX;
    const int ty = t2 % GY;
    const int b  = t2 / GY;

    const int x0 = tx * TX, y0 = ty * TY;

    const float* gb = g0 + (size_t)b * HH * WW;
    const float* rb = rhs + (size_t)b * HH * WW;
    float* ob = out + (size_t)b * HH * WW;

    // per-batch coefficients (d_inv and the -cr sign folded in)
    const float t0 = 1.0f / dx[2 * b + 0], t1 = 1.0f / dx[2 * b + 1];
    const float p0 = t0 * t0, p1 = t1 * t1;
    const float d_inv = 1.0f / (-2.5f * (p0 + p1));
    Coef cf;
    cf.sH1 = -d_inv * (4.0f / 3.0f) * p0;
    cf.sH2 = -d_inv * (-1.0f / 12.0f) * p0;
    cf.sW1 = -d_inv * (4.0f / 3.0f) * p1;
    cf.sW2 = -d_inv * (-1.0f / 12.0f) * p1;

    // ---- fixed work item: 4 rows x 4 cols; lane%32 == col group -> b128 phases
    //      are 32-bank aligned ----
    const bool active = tid < NITEMS;
    const int q = tid >> 5;            // row quad 0..14
    const int cg = tid & 31;           // col group 0..31
    const int r = 2 + 4 * q;           // rows r..r+3 in [2,62)
    const int c = 4 * cg;              // cols c..c+3 in [0,128)
    const int gx0 = x0 - HALO + c;
    const int gy0 = y0 - HALO + r;

    // rhs * d_inv preload (clamped; clamped lanes only feed masked/garbage points)
    float4 rv[4] = {};
    if (active) {
        int gxc = gx0 < 0 ? 0 : (gx0 > WW - 4 ? WW - 4 : gx0);
#pragma unroll
        for (int j = 0; j < 4; ++j) {
            int gy = gy0 + j;
            gy = gy < 0 ? 0 : (gy > HH - 1 ? HH - 1 : gy);
            float4 v = *(const float4*)(rb + (size_t)gy * WW + gxc);
            rv[j] = make_float4(d_inv * v.x, d_inv * v.y, d_inv * v.z, d_inv * v.w);
        }
    }

    // ---- load 128x64 input tile into bufA (clamp-replicate at domain edges) ----
#pragma unroll
    for (int tt = 0; tt < (TWY * NGX) / NTHREADS; ++tt) {
        const int t = tid + tt * NTHREADS;
        const int ly = t >> 5;
        const int c4 = (t & 31) * 4;
        int gy = y0 - HALO + ly;
        gy = gy < 0 ? 0 : (gy > HH - 1 ? HH - 1 : gy);
        const int gxl = x0 - HALO + c4;
        const float* row = gb + (size_t)gy * WW;
        float4 v;
        if (gxl >= 0 && gxl <= WW - 4) {
            v = *(const float4*)(row + gxl);
        } else {
            int xa = gxl + 0; xa = xa < 0 ? 0 : (xa > WW - 1 ? WW - 1 : xa);
            int xb = gxl + 1; xb = xb < 0 ? 0 : (xb > WW - 1 ? WW - 1 : xb);
            int xc = gxl + 2; xc = xc < 0 ? 0 : (xc > WW - 1 ? WW - 1 : xc);
            int xd = gxl + 3; xd = xd < 0 ? 0 : (xd > WW - 1 ? WW - 1 : xd);
            v = make_float4(row[xa], row[xb], row[xc], row[xd]);
        }
        *(float4*)(&bufA[ly * TWX + c4]) = v;
        // rows 0,1,62,63 are frozen y-halo for all sweeps; ping-pong reads them
        // from whichever buffer is src -> mirror into bufB once here.
        if (ly < 2 || ly >= TWY - 2) *(float4*)(&bufB[ly * TWX + c4]) = v;
    }
    __syncthreads();

    // interior fast path (conservative: dependency cone of the stored center
    // strictly inside the frozen ring)
    const bool interior = (x0 - HALO >= 2) && (x0 + TX + HALO <= WW - 2) &&
                          (y0 - HALO >= 2) && (y0 + TY + HALO <= HH - 2);
    if (interior) sweeps_store<false>(bufA, bufB, active, r, c, gx0, gy0, rv, cf, ob, x0, y0);
    else          sweeps_store<true >(bufA, bufB, active, r, c, gx0, gy0, rv, cf, ob, x0, y0);
}

extern "C" void kernel_launch(void* const* d_in, const int* in_sizes, int n_in,
                              void* d_out, int out_size, void* d_ws, size_t ws_size,
                              hipStream_t stream) {
    const float* g0  = (const float*)d_in[0];
    const float* rhs = (const float*)d_in[1];
    const float* dx  = (const float*)d_in[2];
    float* out = (float*)d_out;

    dim3 grid(GX, GY, NB), block(NTHREADS);
    jacobi_fused<<<grid, block, 0, stream>>>(g0, rhs, dx, out);
}